// Round 13
// baseline (175.453 us; speedup 1.0000x reference)
//
#include <hip/hip_runtime.h>

#define BB 8
#define TT 512
#define DD 64
#define S_SCALE 1.2011224087864498f   // sqrt(log2(e)); exp(-u^2) = exp2(-(S*u)^2)

typedef float v2f __attribute__((ext_vector_type(2)));
typedef _Float16 h8 __attribute__((ext_vector_type(8)));
typedef _Float16 v2h __attribute__((ext_vector_type(2)));

static __device__ __forceinline__ float fast_exp2(float v) {
#if __has_builtin(__builtin_amdgcn_exp2f)
    return __builtin_amdgcn_exp2f(v);
#else
    return exp2f(v);
#endif
}
static __device__ __forceinline__ float fast_rcp(float v) {
#if __has_builtin(__builtin_amdgcn_rcpf)
    return __builtin_amdgcn_rcpf(v);
#else
    return 1.0f / v;
#endif
}
static __device__ __forceinline__ v2f pk_fma(v2f a, v2f b, v2f c) {
#if __has_builtin(__builtin_elementwise_fma)
    return __builtin_elementwise_fma(a, b, c);
#else
    return a * b + c;
#endif
}
static __device__ __forceinline__ v2f cvt2(v2h h) {
    return __builtin_convertvector(h, v2f);
}

// ------- kernel 1: v = x@W^T + b ; f16 S*x, f16 v, f32 v -------
__global__ __launch_bounds__(256) void rbf_pre(
    const float* __restrict__ x, const float* __restrict__ W,
    const float* __restrict__ bias,
    _Float16* __restrict__ xh, _Float16* __restrict__ vh,
    float* __restrict__ vv)
{
    const int t = threadIdx.x;
    const int w = t >> 6, l = t & 63;
    const int row = blockIdx.x * 4 + w;
    const float* xr = x + (size_t)row * DD;
    const float* wr = W + (size_t)l * DD;
    float acc = bias[l];
    #pragma unroll
    for (int d = 0; d < DD; d += 4) {
        float4 xv = *(const float4*)(xr + d);
        float4 wv = *(const float4*)(wr + d);
        acc = fmaf(xv.x, wv.x, acc); acc = fmaf(xv.y, wv.y, acc);
        acc = fmaf(xv.z, wv.z, acc); acc = fmaf(xv.w, wv.w, acc);
    }
    xh[(size_t)row * DD + l] = (_Float16)(xr[l] * S_SCALE);
    vh[(size_t)row * DD + l] = (_Float16)acc;
    vv[(size_t)row * DD + l] = acc;
}

// ------- tile body: 1 i-row per wave x 64 j x 64 d, optional mirror -------
// Tiny accumulator live-set (~10 VGPRs) so the scheduler can prefetch many
// LDS loads ahead of the exp/fma chains (ILP, not TLP, is the round-13 bet).
template <bool MIRROR>
static __device__ __forceinline__ void tile_compute(
    const _Float16* xls, const _Float16* vls,
    const float* xis, const float* vis,
    float* __restrict__ orow, float* cbuf, int l, int wau)
{
    v2f nr0 = {0.f, 0.f}, nr1 = {0.f, 0.f};
    v2f nc0 = {0.f, 0.f}, nc1 = {0.f, 0.f};
    v2f dn  = {0.f, 0.f};

    #pragma unroll
    for (int c = 0; c < 8; ++c) {
        h8 xjh = *(const h8*)(xls + l * 72 + c * 8);   // dense ds_read_b128
        h8 vjh = *(const h8*)(vls + l * 72 + c * 8);
        const v2h* xjp = (const v2h*)&xjh;
        const v2h* vjp = (const v2h*)&vjh;
        const v2f* xi2 = (const v2f*)(xis + wau * DD + c * 8);   // bcast
        const v2f* vi2 = (const v2f*)(vis + wau * DD + c * 8);   // bcast
        #pragma unroll
        for (int q = 0; q < 4; ++q) {
            v2f u = xi2[q] - cvt2(xjp[q]);
            u *= u;
            v2f e = {fast_exp2(-u.x), fast_exp2(-u.y)};
            if (q & 1) { nr1 = pk_fma(e, vi2[q], nr1); }
            else       { nr0 = pk_fma(e, vi2[q], nr0); }
            if (MIRROR) {
                if (q & 1) nc1 = pk_fma(e, cvt2(vjp[q]), nc1);
                else       nc0 = pk_fma(e, cvt2(vjp[q]), nc0);
            }
            dn += e;
        }
    }

    float rd = fast_rcp(dn.x + dn.y);
    v2f sr = nr0 + nr1;
    orow[l] = (sr.x + sr.y) * rd;               // coalesced 256 B
    if (MIRROR) {
        v2f sc = nc0 + nc1;
        cbuf[l * 8 + wau] = (sc.x + sc.y) * rd; // stash mirror
    }
}

// ------- kernel 2: symmetric pairwise tiles, 4 i x 64 j, 576/batch -------
// idx<128: diagonal band (ti = 16*jt + r, no mirror); else triangle walk
// (ti < 16*jt, mirror writes out[j, i0..i0+4) too). Grid 4608 -> 18 blocks/CU
// of work (smooth tail); LDS ~20.5 KB -> 7 resident. Coverage: rows cover
// ti <= 16*jt+15, mirrors cover ti < 16*jt -> exact partition of 512^2.
__global__ __launch_bounds__(256, 6) void rbf_sym(
    const float* __restrict__ x,
    const _Float16* __restrict__ xh, const _Float16* __restrict__ vh,
    const float* __restrict__ vv, float* __restrict__ out)
{
    const int bid = blockIdx.x;
    const int b = bid / 576;
    int idx = bid - b * 576;
    int ti, jt, isA;
    if (idx < 128) { jt = idx >> 4; ti = 16 * jt + (idx & 15); isA = 0; }
    else {
        int k = idx - 128, t = 1;
        while (k >= 16 * t) { k -= 16 * t; ++t; }   // <=7 scalar iters
        jt = t; ti = k; isA = 1;
    }
    const int i0 = ti * 4, j0 = jt * 64;

    const int tid = threadIdx.x;
    const int w = tid >> 6, l = tid & 63;
    const int wau = __builtin_amdgcn_readfirstlane(w);

    __shared__ __align__(16) _Float16 xls[64 * 72];  // f16 S*xj tile (144 B rows)
    __shared__ __align__(16) _Float16 vls[64 * 72];  // f16 vj tile
    __shared__ __align__(16) float xis[4 * DD];      // f32 S*xi strip (bcast reads)
    __shared__ __align__(16) float vis[4 * DD];      // f32 vi strip
    __shared__ float cbuf[64 * 8];                   // mirror [j][iloc 0..3]

    // ---- stage j-tiles: 8 KB each, coalesced uint4 ----
    {
        const uint4* xsrc = (const uint4*)(xh + ((size_t)b * TT + j0) * DD);
        const uint4* vsrc = (const uint4*)(vh + ((size_t)b * TT + j0) * DD);
        #pragma unroll
        for (int u = 0; u < 2; ++u) {
            int g = u * 256 + tid;          // 512 uint4 granules per array
            int r = g >> 3, c = g & 7;
            *(uint4*)(xls + r * 72 + c * 8) = xsrc[g];
            *(uint4*)(vls + r * 72 + c * 8) = vsrc[g];
        }
        // ---- stage i-strips: 64 f4 granules each (4 rows x 16) ----
        if (tid < 128) {
            int g = tid & 63;
            int r = g >> 4, c4 = (g & 15) * 4;
            if (tid < 64) {
                float4 v = *(const float4*)(x + ((size_t)(b * TT + i0 + r)) * DD + c4);
                v.x *= S_SCALE; v.y *= S_SCALE; v.z *= S_SCALE; v.w *= S_SCALE;
                *(float4*)(xis + r * DD + c4) = v;
            } else {
                *(float4*)(vis + r * DD + c4) =
                    *(const float4*)(vv + ((size_t)(b * TT + i0 + r)) * DD + c4);
            }
        }
    }
    __syncthreads();

    float* outb = out + (size_t)b * TT * TT;
    float* orow = outb + (size_t)(i0 + wau) * TT + j0;

    if (isA) tile_compute<true >(xls, vls, xis, vis, orow, cbuf, l, wau);
    else     tile_compute<false>(xls, vls, xis, vis, orow, cbuf, l, wau);

    __syncthreads();
    if (isA && tid < 64) {
        // flush mirror: out[j0+j][i0 .. i0+4), one 16-B aligned float4 per row
        float4 cv = *(const float4*)(cbuf + tid * 8);
        *(float4*)(outb + (size_t)(j0 + tid) * TT + i0) = cv;
    }
}

extern "C" void kernel_launch(void* const* d_in, const int* in_sizes, int n_in,
                              void* d_out, int out_size, void* d_ws, size_t ws_size,
                              hipStream_t stream) {
    const float* x    = (const float*)d_in[0];
    const float* W    = (const float*)d_in[1];
    const float* bias = (const float*)d_in[2];
    float* out        = (float*)d_out;

    _Float16* xh = (_Float16*)d_ws;                       // 0.5 MB
    _Float16* vh = (_Float16*)((char*)d_ws + (1 << 19));  // 0.5 MB
    float*    vv = (float*)((char*)d_ws + (1 << 20));     // 1 MB

    rbf_pre<<<BB * TT / 4, 256, 0, stream>>>(x, W, bias, xh, vh, vv);
    rbf_sym<<<BB * 576, 256, 0, stream>>>(x, xh, vh, vv, out);
}

// Round 14
// 87.862 us; speedup vs baseline: 1.9969x; 1.9969x over previous
//
#include <hip/hip_runtime.h>

#define BB 8
#define TT 512
#define DD 64
#define S_SCALE 1.2011224087864498f   // sqrt(log2(e)); exp(-u^2) = exp2(-(S*u)^2)

typedef float v2f __attribute__((ext_vector_type(2)));
typedef _Float16 h8 __attribute__((ext_vector_type(8)));
typedef _Float16 v2h __attribute__((ext_vector_type(2)));

static __device__ __forceinline__ float fast_exp2(float v) {
#if __has_builtin(__builtin_amdgcn_exp2f)
    return __builtin_amdgcn_exp2f(v);
#else
    return exp2f(v);
#endif
}
static __device__ __forceinline__ float fast_rcp(float v) {
#if __has_builtin(__builtin_amdgcn_rcpf)
    return __builtin_amdgcn_rcpf(v);
#else
    return 1.0f / v;
#endif
}
static __device__ __forceinline__ v2f pk_fma(v2f a, v2f b, v2f c) {
#if __has_builtin(__builtin_elementwise_fma)
    return __builtin_elementwise_fma(a, b, c);
#else
    return a * b + c;
#endif
}
static __device__ __forceinline__ v2f cvt2(v2h h) {
    return __builtin_convertvector(h, v2f);
}

// ------- kernel 1: v = x@W^T + b ; f16 S*x and f16 v -------
__global__ __launch_bounds__(256) void rbf_pre(
    const float* __restrict__ x, const float* __restrict__ W,
    const float* __restrict__ bias,
    _Float16* __restrict__ xh, _Float16* __restrict__ vh)
{
    const int t = threadIdx.x;
    const int w = t >> 6, l = t & 63;
    const int row = blockIdx.x * 4 + w;
    const float* xr = x + (size_t)row * DD;
    const float* wr = W + (size_t)l * DD;
    float acc = bias[l];
    #pragma unroll
    for (int d = 0; d < DD; d += 4) {
        float4 xv = *(const float4*)(xr + d);
        float4 wv = *(const float4*)(wr + d);
        acc = fmaf(xv.x, wv.x, acc); acc = fmaf(xv.y, wv.y, acc);
        acc = fmaf(xv.z, wv.z, acc); acc = fmaf(xv.w, wv.w, acc);
    }
    xh[(size_t)row * DD + l] = (_Float16)(xr[l] * S_SCALE);
    vh[(size_t)row * DD + l] = (_Float16)acc;
}

// ------- tile body: 2 i-rows (per wave) x 64 j x 64 d, optional mirror -------
// ALL operands f16: per c-iter the wave issues 2 dense ds_read_b128 (xj/vj)
// + 4 broadcast ds_read_b128 (xi/vi for 2 rows) = 6 LDS instrs (vs 10 with
// f32 i-strips) -- the LDS unit is the widest pipe, this is the A/B lever.
template <bool MIRROR>
static __device__ __forceinline__ void tile_compute(
    const _Float16* xls, const _Float16* vls,
    const _Float16* xis, const _Float16* vis,
    float* __restrict__ orow0, float* cbuf, int l, int wau)
{
    v2f nr[2][2], nc[2][2], dn[2];
    #pragma unroll
    for (int r = 0; r < 2; ++r) {
        nr[r][0] = (v2f){0.f, 0.f}; nr[r][1] = (v2f){0.f, 0.f};
        nc[r][0] = (v2f){0.f, 0.f}; nc[r][1] = (v2f){0.f, 0.f};
        dn[r]    = (v2f){0.f, 0.f};
    }

    #pragma unroll
    for (int c = 0; c < 8; ++c) {
        h8 xjh = *(const h8*)(xls + l * 72 + c * 8);   // dense ds_read_b128
        h8 vjh = *(const h8*)(vls + l * 72 + c * 8);
        const v2h* xjp = (const v2h*)&xjh;
        const v2h* vjp = (const v2h*)&vjh;
        #pragma unroll
        for (int r = 0; r < 2; ++r) {
            h8 xih = *(const h8*)(xis + (wau * 2 + r) * DD + c * 8);  // bcast b128
            h8 vih = *(const h8*)(vis + (wau * 2 + r) * DD + c * 8);  // bcast b128
            const v2h* xip = (const v2h*)&xih;
            const v2h* vip = (const v2h*)&vih;
            #pragma unroll
            for (int q = 0; q < 4; ++q) {
                v2f u = cvt2(xip[q]) - cvt2(xjp[q]);
                u *= u;
                v2f e = {fast_exp2(-u.x), fast_exp2(-u.y)};
                nr[r][q & 1] = pk_fma(e, cvt2(vip[q]), nr[r][q & 1]);
                if (MIRROR) nc[r][q & 1] = pk_fma(e, cvt2(vjp[q]), nc[r][q & 1]);
                dn[r] += e;
            }
        }
    }

    #pragma unroll
    for (int r = 0; r < 2; ++r) {
        float rd = fast_rcp(dn[r].x + dn[r].y);
        v2f sr = nr[r][0] + nr[r][1];
        orow0[(size_t)r * TT + l] = (sr.x + sr.y) * rd;   // coalesced 256 B
        if (MIRROR) {
            v2f sc = nc[r][0] + nc[r][1];
            cbuf[l * 12 + wau * 2 + r] = (sc.x + sc.y) * rd;
        }
    }
}

// ------- kernel 2: symmetric pairwise tiles, 8 i x 64 j, 288/batch -------
// R10-validated mapping: idx<64 diagonal band (no mirror), else triangle walk
// (mirror writes out[j, i0..i0+8) too, 32-B chunks). Grid 2304.
__global__ __launch_bounds__(256, 6) void rbf_sym(
    const _Float16* __restrict__ xh, const _Float16* __restrict__ vh,
    float* __restrict__ out)
{
    const int bid = blockIdx.x;
    const int b = bid / 288;
    int idx = bid - b * 288;
    int ti, jt, isA;
    if (idx < 64) { jt = idx >> 3; ti = 8 * jt + (idx & 7); isA = 0; }
    else {
        int k = idx - 64, t = 1;
        while (k >= 8 * t) { k -= 8 * t; ++t; }   // <=7 scalar iters
        jt = t; ti = k; isA = 1;
    }
    const int i0 = ti * 8, j0 = jt * 64;

    const int tid = threadIdx.x;
    const int w = tid >> 6, l = tid & 63;
    const int wau = __builtin_amdgcn_readfirstlane(w);

    __shared__ __align__(16) _Float16 xls[64 * 72];  // f16 S*xj tile (144 B rows)
    __shared__ __align__(16) _Float16 vls[64 * 72];  // f16 vj tile
    __shared__ __align__(16) _Float16 xis[8 * DD];   // f16 S*xi strip (bcast reads)
    __shared__ __align__(16) _Float16 vis[8 * DD];   // f16 vi strip
    __shared__ float cbuf[64 * 12];                  // mirror [j][iloc 0..7]

    // ---- stage j-tiles: 8 KB each, coalesced uint4 ----
    {
        const uint4* xsrc = (const uint4*)(xh + ((size_t)b * TT + j0) * DD);
        const uint4* vsrc = (const uint4*)(vh + ((size_t)b * TT + j0) * DD);
        #pragma unroll
        for (int u = 0; u < 2; ++u) {
            int g = u * 256 + tid;          // 512 uint4 granules per array
            int r = g >> 3, c = g & 7;
            *(uint4*)(xls + r * 72 + c * 8) = xsrc[g];
            *(uint4*)(vls + r * 72 + c * 8) = vsrc[g];
        }
        // ---- stage i-strips (f16, 1 KB each): 64 uint4 granules per array ----
        if (tid < 128) {
            int g = tid & 63;               // 64 granules = 8 rows x 8
            const uint4* isrc = (tid < 64)
                ? (const uint4*)(xh + ((size_t)b * TT + i0) * DD)
                : (const uint4*)(vh + ((size_t)b * TT + i0) * DD);
            _Float16* idst = (tid < 64) ? xis : vis;
            *(uint4*)(idst + g * 8) = isrc[g];
        }
    }
    __syncthreads();

    float* outb  = out + (size_t)b * TT * TT;
    float* orow0 = outb + (size_t)(i0 + wau * 2) * TT + j0;

    if (isA) tile_compute<true >(xls, vls, xis, vis, orow0, cbuf, l, wau);
    else     tile_compute<false>(xls, vls, xis, vis, orow0, cbuf, l, wau);

    __syncthreads();
    if (isA && tid < 128) {
        // flush mirror: out[j0+j][i0 .. i0+8), 16-B aligned float4 per thread
        int j = tid >> 1, qf = (tid & 1) * 4;
        float4 cv = *(const float4*)(cbuf + j * 12 + qf);
        *(float4*)(outb + (size_t)(j0 + j) * TT + i0 + qf) = cv;
    }
}

extern "C" void kernel_launch(void* const* d_in, const int* in_sizes, int n_in,
                              void* d_out, int out_size, void* d_ws, size_t ws_size,
                              hipStream_t stream) {
    const float* x    = (const float*)d_in[0];
    const float* W    = (const float*)d_in[1];
    const float* bias = (const float*)d_in[2];
    float* out        = (float*)d_out;

    _Float16* xh = (_Float16*)d_ws;                       // 0.5 MB
    _Float16* vh = (_Float16*)((char*)d_ws + (1 << 19));  // 0.5 MB

    rbf_pre<<<BB * TT / 4, 256, 0, stream>>>(x, W, bias, xh, vh);
    rbf_sym<<<BB * 288, 256, 0, stream>>>(xh, vh, out);
}

// Round 15
// 83.616 us; speedup vs baseline: 2.0983x; 1.0508x over previous
//
#include <hip/hip_runtime.h>

#define BB 8
#define TT 512
#define DD 64
#define S_SCALE 1.2011224087864498f   // sqrt(log2(e)); exp(-u^2) = exp2(-(S*u)^2)

typedef float v2f __attribute__((ext_vector_type(2)));
typedef _Float16 h8 __attribute__((ext_vector_type(8)));
typedef _Float16 v2h __attribute__((ext_vector_type(2)));

static __device__ __forceinline__ float fast_exp2(float v) {
#if __has_builtin(__builtin_amdgcn_exp2f)
    return __builtin_amdgcn_exp2f(v);
#else
    return exp2f(v);
#endif
}
static __device__ __forceinline__ float fast_rcp(float v) {
#if __has_builtin(__builtin_amdgcn_rcpf)
    return __builtin_amdgcn_rcpf(v);
#else
    return 1.0f / v;
#endif
}
static __device__ __forceinline__ v2f pk_fma(v2f a, v2f b, v2f c) {
#if __has_builtin(__builtin_elementwise_fma)
    return __builtin_elementwise_fma(a, b, c);
#else
    return a * b + c;
#endif
}
static __device__ __forceinline__ v2f cvt2(v2h h) {
    return __builtin_convertvector(h, v2f);
}

// ------- kernel 1: v = x@W^T + b ; f16 S*x, f16 v, f32 v -------
__global__ __launch_bounds__(256) void rbf_pre(
    const float* __restrict__ x, const float* __restrict__ W,
    const float* __restrict__ bias,
    _Float16* __restrict__ xh, _Float16* __restrict__ vh,
    float* __restrict__ vv)
{
    const int t = threadIdx.x;
    const int w = t >> 6, l = t & 63;
    const int row = blockIdx.x * 4 + w;
    const float* xr = x + (size_t)row * DD;
    const float* wr = W + (size_t)l * DD;
    float acc = bias[l];
    #pragma unroll
    for (int d = 0; d < DD; d += 4) {
        float4 xv = *(const float4*)(xr + d);
        float4 wv = *(const float4*)(wr + d);
        acc = fmaf(xv.x, wv.x, acc); acc = fmaf(xv.y, wv.y, acc);
        acc = fmaf(xv.z, wv.z, acc); acc = fmaf(xv.w, wv.w, acc);
    }
    xh[(size_t)row * DD + l] = (_Float16)(xr[l] * S_SCALE);
    vh[(size_t)row * DD + l] = (_Float16)acc;
    vv[(size_t)row * DD + l] = acc;
}

// ------- tile body: 2 i-rows (per wave) x 64 j x 64 d, optional mirror -------
// f16 j-operands from LDS (dense ds_read_b128, lazy 2-elem cvt), f32 i-operands
// as LDS broadcasts. In-lane accumulation, no cross-lane reductions.
template <bool MIRROR>
static __device__ __forceinline__ void tile_compute(
    const _Float16* xls, const _Float16* vls,
    const float* xis, const float* vis,
    float* __restrict__ orow0, float* cbuf, int l, int wau)
{
    v2f nr[2][2], nc[2][2], dn[2];
    #pragma unroll
    for (int r = 0; r < 2; ++r) {
        nr[r][0] = (v2f){0.f, 0.f}; nr[r][1] = (v2f){0.f, 0.f};
        nc[r][0] = (v2f){0.f, 0.f}; nc[r][1] = (v2f){0.f, 0.f};
        dn[r]    = (v2f){0.f, 0.f};
    }

    #pragma unroll
    for (int c = 0; c < 8; ++c) {
        h8 xjh = *(const h8*)(xls + l * 72 + c * 8);   // dense ds_read_b128
        h8 vjh = *(const h8*)(vls + l * 72 + c * 8);
        const v2h* xjp = (const v2h*)&xjh;             // lane-local sub-vectors
        const v2h* vjp = (const v2h*)&vjh;
        #pragma unroll
        for (int r = 0; r < 2; ++r) {
            const v2f* xi2 = (const v2f*)(xis + (wau * 2 + r) * DD + c * 8); // bcast
            const v2f* vi2 = (const v2f*)(vis + (wau * 2 + r) * DD + c * 8); // bcast
            #pragma unroll
            for (int q = 0; q < 4; ++q) {
                v2f u = xi2[q] - cvt2(xjp[q]);
                u *= u;
                v2f e = {fast_exp2(-u.x), fast_exp2(-u.y)};
                nr[r][q & 1] = pk_fma(e, vi2[q], nr[r][q & 1]);
                if (MIRROR) nc[r][q & 1] = pk_fma(e, cvt2(vjp[q]), nc[r][q & 1]);
                dn[r] += e;
            }
        }
    }

    #pragma unroll
    for (int r = 0; r < 2; ++r) {
        float rd = fast_rcp(dn[r].x + dn[r].y);
        v2f sr = nr[r][0] + nr[r][1];
        orow0[(size_t)r * TT + l] = (sr.x + sr.y) * rd;   // coalesced 256 B
        if (MIRROR) {
            v2f sc = nc[r][0] + nc[r][1];
            cbuf[l * 12 + wau * 2 + r] = (sc.x + sc.y) * rd;
        }
    }
}

// ------- kernel 2: symmetric pairwise tiles, 8 i x 64 j, 288/batch -------
// idx<64: diagonal band (no mirror); else triangle walk (mirror writes
// out[j, i0..i0+8) too). Best measured configuration (R10/R12, 84.8 us).
__global__ __launch_bounds__(256, 8) void rbf_sym(
    const float* __restrict__ x,
    const _Float16* __restrict__ xh, const _Float16* __restrict__ vh,
    const float* __restrict__ vv, float* __restrict__ out)
{
    const int bid = blockIdx.x;
    const int b = bid / 288;
    int idx = bid - b * 288;
    int ti, jt, isA;
    if (idx < 64) { jt = idx >> 3; ti = 8 * jt + (idx & 7); isA = 0; }
    else {
        int k = idx - 64, t = 1;
        while (k >= 8 * t) { k -= 8 * t; ++t; }   // <=7 scalar iters
        jt = t; ti = k; isA = 1;
    }
    const int i0 = ti * 8, j0 = jt * 64;

    const int tid = threadIdx.x;
    const int w = tid >> 6, l = tid & 63;
    const int wau = __builtin_amdgcn_readfirstlane(w);

    __shared__ __align__(16) _Float16 xls[64 * 72];  // f16 S*xj tile (144 B rows)
    __shared__ __align__(16) _Float16 vls[64 * 72];  // f16 vj tile
    __shared__ __align__(16) float xis[8 * DD];      // f32 S*xi strip (bcast reads)
    __shared__ __align__(16) float vis[8 * DD];      // f32 vi strip
    __shared__ float cbuf[64 * 12];                  // mirror [j][iloc 0..7]

    // ---- stage j-tiles: 8 KB each, coalesced uint4 ----
    {
        const uint4* xsrc = (const uint4*)(xh + ((size_t)b * TT + j0) * DD);
        const uint4* vsrc = (const uint4*)(vh + ((size_t)b * TT + j0) * DD);
        #pragma unroll
        for (int u = 0; u < 2; ++u) {
            int g = u * 256 + tid;          // 512 uint4 granules per array
            int r = g >> 3, c = g & 7;
            *(uint4*)(xls + r * 72 + c * 8) = xsrc[g];
            *(uint4*)(vls + r * 72 + c * 8) = vsrc[g];
        }
        // ---- stage i-strips: tid<128 -> S*x (f32), else -> v (f32) ----
        int g = tid & 127;                  // 128 f4 granules = 8 rows x 16
        int r = g >> 4, c4 = (g & 15) * 4;
        if (tid < 128) {
            float4 v = *(const float4*)(x + ((size_t)(b * TT + i0 + r)) * DD + c4);
            v.x *= S_SCALE; v.y *= S_SCALE; v.z *= S_SCALE; v.w *= S_SCALE;
            *(float4*)(xis + r * DD + c4) = v;
        } else {
            *(float4*)(vis + r * DD + c4) =
                *(const float4*)(vv + ((size_t)(b * TT + i0 + r)) * DD + c4);
        }
    }
    __syncthreads();

    float* outb  = out + (size_t)b * TT * TT;
    float* orow0 = outb + (size_t)(i0 + wau * 2) * TT + j0;

    if (isA) tile_compute<true >(xls, vls, xis, vis, orow0, cbuf, l, wau);
    else     tile_compute<false>(xls, vls, xis, vis, orow0, cbuf, l, wau);

    __syncthreads();
    if (isA && tid < 128) {
        // flush mirror: out[j0+j][i0 .. i0+8), 16-B aligned float4 per thread
        int j = tid >> 1, qf = (tid & 1) * 4;
        float4 cv = *(const float4*)(cbuf + j * 12 + qf);
        *(float4*)(outb + (size_t)(j0 + j) * TT + i0 + qf) = cv;
    }
}

extern "C" void kernel_launch(void* const* d_in, const int* in_sizes, int n_in,
                              void* d_out, int out_size, void* d_ws, size_t ws_size,
                              hipStream_t stream) {
    const float* x    = (const float*)d_in[0];
    const float* W    = (const float*)d_in[1];
    const float* bias = (const float*)d_in[2];
    float* out        = (float*)d_out;

    _Float16* xh = (_Float16*)d_ws;                       // 0.5 MB
    _Float16* vh = (_Float16*)((char*)d_ws + (1 << 19));  // 0.5 MB
    float*    vv = (float*)((char*)d_ws + (1 << 20));     // 1 MB

    rbf_pre<<<BB * TT / 4, 256, 0, stream>>>(x, W, bias, xh, vh, vv);
    rbf_sym<<<BB * 288, 256, 0, stream>>>(x, xh, vh, vv, out);
}